// Round 3
// baseline (52.032 us; speedup 1.0000x reference)
//
#include <hip/hip_runtime.h>
#include <math.h>

// Problem constants (from reference): eps_t, y_t are (256, 24, 4096) f32.
#define BATCH_SZ   256
#define D_EVENT    (24 * 4096)                  // 98304
#define N_TOTAL    (BATCH_SZ * D_EVENT)         // 25,165,824

#define BLOCK      256
#define GRID       2048
#define STRIDE     (GRID * BLOCK)               // 524,288 threads
#define N4         (N_TOTAL / 4)                // 6,291,456 float4
#define ITERS      (N4 / STRIDE)                // 12, exact — no remainder
#define GROUP      6                            // 12 float4 loads in flight

// Masked sum-of-squares reduction. 2 fully-unrolled groups of 6 iterations:
// 12 independent float4 loads issued back-to-back before any use.
// __launch_bounds__(256,4): cap 128 VGPR (16 waves/CU) — explicitly trade
// occupancy for in-flight loads (R2 showed compiler clamped to 32 VGPR and
// serialized the load groups).
__global__ void __launch_bounds__(BLOCK, 4)
mgd_reduce_kernel(const float4* __restrict__ eps,
                  const float4* __restrict__ y,
                  float* __restrict__ acc) {
    int tid = blockIdx.x * BLOCK + threadIdx.x;
    float s0 = 0.0f, s1 = 0.0f, s2 = 0.0f, s3 = 0.0f;

    #pragma unroll
    for (int k = 0; k < ITERS; k += GROUP) {
        float4 e[GROUP], g[GROUP];
        // Issue all 12 loads first — static indices, stays in registers.
        #pragma unroll
        for (int j = 0; j < GROUP; ++j) e[j] = eps[tid + (k + j) * STRIDE];
        #pragma unroll
        for (int j = 0; j < GROUP; ++j) g[j] = y  [tid + (k + j) * STRIDE];
        // Branchless masked square-accumulate, 4 independent chains.
        #pragma unroll
        for (int j = 0; j < GROUP; ++j) {
            float m;
            m = (g[j].x != 0.0f) ? e[j].x : 0.0f; s0 = fmaf(m, m, s0);
            m = (g[j].y != 0.0f) ? e[j].y : 0.0f; s1 = fmaf(m, m, s1);
            m = (g[j].z != 0.0f) ? e[j].z : 0.0f; s2 = fmaf(m, m, s2);
            m = (g[j].w != 0.0f) ? e[j].w : 0.0f; s3 = fmaf(m, m, s3);
        }
    }
    float sum = (s0 + s1) + (s2 + s3);

    // Wave-64 shuffle reduction.
    #pragma unroll
    for (int off = 32; off > 0; off >>= 1)
        sum += __shfl_down(sum, off, 64);
    __shared__ float lds[BLOCK / 64];
    int lane = threadIdx.x & 63;
    int wave = threadIdx.x >> 6;
    if (lane == 0) lds[wave] = sum;
    __syncthreads();
    if (threadIdx.x == 0) {
        float s = (lds[0] + lds[1]) + (lds[2] + lds[3]);
        atomicAdd(acc, s);                      // device-scope by default
    }
}

// Single-thread finalize: softplus + closed-form loss.
__global__ void mgd_finalize_kernel(const float* __restrict__ acc,
                                    const float* __restrict__ sigma,
                                    float* __restrict__ out) {
    float sg = sigma[0];
    float s = fmaxf(sg, 0.0f) + log1pf(expf(-fabsf(sg)));  // stable softplus
    const float LOG_2PI = 1.8378770664093453f;
    float quad_mean = acc[0] / ((float)BATCH_SZ * s);
    out[0] = 0.5f * (quad_mean + (float)D_EVENT * (LOG_2PI + logf(s)));
}

extern "C" void kernel_launch(void* const* d_in, const int* in_sizes, int n_in,
                              void* d_out, int out_size, void* d_ws, size_t ws_size,
                              hipStream_t stream) {
    const float4* eps   = (const float4*)d_in[0];
    const float4* y     = (const float4*)d_in[1];
    const float*  sigma = (const float*)d_in[2];
    float* out = (float*)d_out;
    float* acc = (float*)d_ws;

    // d_ws is poisoned once (0xAA) and never re-poisoned: zero it each call.
    hipMemsetAsync(acc, 0, sizeof(float), stream);

    mgd_reduce_kernel<<<GRID, BLOCK, 0, stream>>>(eps, y, acc);
    mgd_finalize_kernel<<<1, 1, 0, stream>>>(acc, sigma, out);
}

// Round 4
// 37.945 us; speedup vs baseline: 1.3712x; 1.3712x over previous
//
#include <hip/hip_runtime.h>
#include <math.h>

// Problem constants (from reference): eps_t, y_t are (256, 24, 4096) f32.
#define BATCH_SZ   256
#define D_EVENT    (24 * 4096)                  // 98304
#define N_TOTAL    (BATCH_SZ * D_EVENT)         // 25,165,824

#define BLOCK      256
#define GRID       4096
#define STRIDE     (GRID * BLOCK)               // 1,048,576 threads
#define N4         (N_TOTAL / 4)                // 6,291,456 float4
#define ITERS      (N4 / STRIDE)                // 6, exact — no remainder
#define GROUP      3                            // 6 float4 loads in flight

// Masked sum-of-squares reduction. R3 lesson: deep (12) load groups +
// VGPR headroom regressed (compiler serialized anyway, occupancy fell).
// Use moderate MLP (6 loads in flight) x high TLP (4096 blocks).
// Each block writes its partial to ws[blockIdx.x]: deterministic
// overwrite, no atomic, no zero-init -> removes the memset graph node.
__global__ void __launch_bounds__(BLOCK)
mgd_reduce_kernel(const float4* __restrict__ eps,
                  const float4* __restrict__ y,
                  float* __restrict__ partials) {
    int tid = blockIdx.x * BLOCK + threadIdx.x;
    float s0 = 0.0f, s1 = 0.0f, s2 = 0.0f, s3 = 0.0f;

    #pragma unroll
    for (int k = 0; k < ITERS; k += GROUP) {
        float4 e[GROUP], g[GROUP];
        #pragma unroll
        for (int j = 0; j < GROUP; ++j) e[j] = eps[tid + (k + j) * STRIDE];
        #pragma unroll
        for (int j = 0; j < GROUP; ++j) g[j] = y  [tid + (k + j) * STRIDE];
        #pragma unroll
        for (int j = 0; j < GROUP; ++j) {
            float m;
            m = (g[j].x != 0.0f) ? e[j].x : 0.0f; s0 = fmaf(m, m, s0);
            m = (g[j].y != 0.0f) ? e[j].y : 0.0f; s1 = fmaf(m, m, s1);
            m = (g[j].z != 0.0f) ? e[j].z : 0.0f; s2 = fmaf(m, m, s2);
            m = (g[j].w != 0.0f) ? e[j].w : 0.0f; s3 = fmaf(m, m, s3);
        }
    }
    float sum = (s0 + s1) + (s2 + s3);

    // Wave-64 shuffle reduction.
    #pragma unroll
    for (int off = 32; off > 0; off >>= 1)
        sum += __shfl_down(sum, off, 64);
    __shared__ float lds[BLOCK / 64];
    int lane = threadIdx.x & 63;
    int wave = threadIdx.x >> 6;
    if (lane == 0) lds[wave] = sum;
    __syncthreads();
    if (threadIdx.x == 0)
        partials[blockIdx.x] = (lds[0] + lds[1]) + (lds[2] + lds[3]);
}

// One 256-thread block: reduce 4096 partials + closed-form loss.
__global__ void __launch_bounds__(BLOCK)
mgd_finalize_kernel(const float* __restrict__ partials,
                    const float* __restrict__ sigma,
                    float* __restrict__ out) {
    const float4* p4 = (const float4*)partials;
    float sum = 0.0f;
    #pragma unroll
    for (int k = 0; k < GRID / 4 / BLOCK; ++k) {          // 4 iters
        float4 p = p4[threadIdx.x + k * BLOCK];
        sum += (p.x + p.y) + (p.z + p.w);
    }
    #pragma unroll
    for (int off = 32; off > 0; off >>= 1)
        sum += __shfl_down(sum, off, 64);
    __shared__ float lds[BLOCK / 64];
    int lane = threadIdx.x & 63;
    int wave = threadIdx.x >> 6;
    if (lane == 0) lds[wave] = sum;
    __syncthreads();
    if (threadIdx.x == 0) {
        float acc = (lds[0] + lds[1]) + (lds[2] + lds[3]);
        float sg = sigma[0];
        float s = fmaxf(sg, 0.0f) + log1pf(expf(-fabsf(sg)));  // softplus
        const float LOG_2PI = 1.8378770664093453f;
        float quad_mean = acc / ((float)BATCH_SZ * s);
        out[0] = 0.5f * (quad_mean + (float)D_EVENT * (LOG_2PI + logf(s)));
    }
}

extern "C" void kernel_launch(void* const* d_in, const int* in_sizes, int n_in,
                              void* d_out, int out_size, void* d_ws, size_t ws_size,
                              hipStream_t stream) {
    const float4* eps   = (const float4*)d_in[0];
    const float4* y     = (const float4*)d_in[1];
    const float*  sigma = (const float*)d_in[2];
    float* out      = (float*)d_out;
    float* partials = (float*)d_ws;            // 4096 floats = 16 KB scratch

    mgd_reduce_kernel  <<<GRID, BLOCK, 0, stream>>>(eps, y, partials);
    mgd_finalize_kernel<<<1,    BLOCK, 0, stream>>>(partials, sigma, out);
}